// Round 11
// baseline (105.468 us; speedup 1.0000x reference)
//
#include <hip/hip_runtime.h>
#include <math.h>

#define NN 100000          // nodes
#define NE 1600000         // edges
#define NBKT 391           // buckets of 256 nodes: (NN+255)/256
#define LPS  (NBKT + 1)    // lpre row stride (392)
#define EPB 2048           // edges per sort chunk
#define NPB ((NE + EPB - 1) / EPB)        // 782 chunks
#define TOTC (NBKT * NPB)                 // 305,762 cells (bucket-major)
#define SBLK 2048                         // scan elems per block
#define NSB ((TOTC + SBLK - 1) / SBLK)    // 150 scan blocks
#define LBUF 6144          // per-bucket LDS entry cap (mean 4092, +32 sigma)

typedef unsigned int uint;
typedef unsigned short ushort;
typedef __attribute__((ext_vector_type(8))) short bfx8;
typedef __attribute__((ext_vector_type(4))) float f32x4;

static __device__ __forceinline__ ushort f2bf(float f) {
  uint u = __float_as_uint(f);
  uint r = (u + 0x7fffu + ((u >> 16) & 1u)) >> 16;   // RNE
  return (ushort)r;
}
static __device__ __forceinline__ float bf2f(ushort v) {
  return __uint_as_float((uint)v << 16);
}
static __device__ __forceinline__ bfx8 cvt8(float4 a, float4 b) {
  bfx8 r;
  r[0] = (short)f2bf(a.x); r[1] = (short)f2bf(a.y);
  r[2] = (short)f2bf(a.z); r[3] = (short)f2bf(a.w);
  r[4] = (short)f2bf(b.x); r[5] = (short)f2bf(b.y);
  r[6] = (short)f2bf(b.z); r[7] = (short)f2bf(b.w);
  return r;
}

// ---------------- Kernel A: h = x @ W^T via bf16 MFMA, fused s_src/s_dst ----
__global__ __launch_bounds__(256) void k_h(
    const float* __restrict__ x, const float* __restrict__ W,
    const float* __restrict__ a_src, const float* __restrict__ a_dst,
    ushort* __restrict__ h16, float* __restrict__ ssrc, float* __restrict__ sdst)
{
  __shared__ __align__(16) ushort ws[64 * 128];   // 16KB
  const int t = threadIdx.x;
  const int base = blockIdx.x * 64;
  const float4* x4 = (const float4*)x;
  const float4* W4 = (const float4*)W;

#pragma unroll
  for (int q = 0; q < 8; ++q) {
    int f = q * 256 + t;
    int row = f >> 5, c4 = f & 31;
    float4 v = W4[f];
    ushort4 pk = make_ushort4(f2bf(v.x), f2bf(v.y), f2bf(v.z), f2bf(v.w));
    int byte = row * 256 + ((c4 * 8) ^ ((row & 7) << 4));
    *(ushort4*)((char*)ws + byte) = pk;
  }

  const int wid = t >> 6;
  const int lane = t & 63;
  const int lg = lane >> 4;    // k-group / C row group
  const int lr = lane & 15;    // A row / B col / C col

  const int node = base + wid * 16 + lr;
  const bool ok = node < NN;
  const float4* xr = x4 + (size_t)node * 32;

  float4 xa[4][2];
#pragma unroll
  for (int ks = 0; ks < 4; ++ks) {
    xa[ks][0] = ok ? xr[ks * 8 + lg * 2]     : make_float4(0.f, 0.f, 0.f, 0.f);
    xa[ks][1] = ok ? xr[ks * 8 + lg * 2 + 1] : make_float4(0.f, 0.f, 0.f, 0.f);
  }
  __syncthreads();

  f32x4 acc[4];
#pragma unroll
  for (int ng = 0; ng < 4; ++ng) acc[ng] = (f32x4){0.f, 0.f, 0.f, 0.f};

#pragma unroll
  for (int ks = 0; ks < 4; ++ks) {
    int kb = ks * 64 + lg * 16;
    bfx8 af = cvt8(xa[ks][0], xa[ks][1]);
    bfx8 bfr[4];
#pragma unroll
    for (int ng = 0; ng < 4; ++ng) {
      int row = ng * 16 + lr;
      bfr[ng] = *(const bfx8*)((const char*)ws + row * 256 + (kb ^ ((row & 7) << 4)));
    }
#pragma unroll
    for (int ng = 0; ng < 4; ++ng)
      acc[ng] = __builtin_amdgcn_mfma_f32_16x16x32_bf16(af, bfr[ng], acc[ng], 0, 0, 0);
  }

  float as_[4], ad_[4];
#pragma unroll
  for (int ng = 0; ng < 4; ++ng) { as_[ng] = a_src[ng * 16 + lr]; ad_[ng] = a_dst[ng * 16 + lr]; }
#pragma unroll
  for (int r = 0; r < 4; ++r) {
    int nout = base + wid * 16 + lg * 4 + r;
    float ps = 0.f, pd = 0.f;
#pragma unroll
    for (int ng = 0; ng < 4; ++ng) { ps += acc[ng][r] * as_[ng]; pd += acc[ng][r] * ad_[ng]; }
#pragma unroll
    for (int m = 1; m < 16; m <<= 1) { ps += __shfl_xor(ps, m); pd += __shfl_xor(pd, m); }
    if (lr == 0 && nout < NN) { ssrc[nout] = ps; sdst[nout] = pd; }
    if (nout < NN) {
#pragma unroll
      for (int ng = 0; ng < 4; ++ng)
        h16[(size_t)nout * 64 + ng * 16 + lr] = f2bf(acc[ng][r]);
    }
  }
}

// ---------------- k_sort: per-chunk bucket sort in LDS (512 thr), coalesced out --
__global__ __launch_bounds__(512) void k_sort(const int* __restrict__ ei,
                                              const float* __restrict__ ssrc,
                                              int* __restrict__ cnt,
                                              int* __restrict__ lpre,
                                              int2* __restrict__ stage)
{
  __shared__ int hh[NBKT];
  __shared__ int sums[512];
  __shared__ int2 sbuf[EPB];    // 16KB
  const int t = threadIdx.x, c = blockIdx.x;
  for (int i = t; i < NBKT; i += 512) hh[i] = 0;
  __syncthreads();

  const int base = c * EPB;
  const int nloc = min(EPB, NE - base);
  int my_src[EPB / 512], my_dst[EPB / 512];
#pragma unroll
  for (int q = 0; q < EPB / 512; ++q) {
    int e = base + q * 512 + t;
    if (e < NE) {
      my_src[q] = ei[e];
      my_dst[q] = ei[NE + e];
      atomicAdd(&hh[my_dst[q] >> 8], 1);
    } else my_dst[q] = -1;
  }
  __syncthreads();

  // exclusive scan of hh[NBKT], one elem/thread (NBKT < 512)
  int v = (t < NBKT) ? hh[t] : 0;
  sums[t] = v;
  __syncthreads();
  for (int off = 1; off < 512; off <<= 1) {
    int u = (t >= off) ? sums[t - off] : 0;
    __syncthreads();
    sums[t] += u;
    __syncthreads();
  }
  int ex = sums[t] - v;
  if (t < NBKT) {
    hh[t] = ex;
    lpre[c * LPS + t] = ex;
    cnt[t * NPB + c] = v;
  }
  if (t == 0) lpre[c * LPS + NBKT] = nloc;
  __syncthreads();

#pragma unroll
  for (int q = 0; q < EPB / 512; ++q) {
    if (my_dst[q] >= 0) {
      int dst = my_dst[q], src = my_src[q];
      int pos = atomicAdd(&hh[dst >> 8], 1);
      sbuf[pos] = make_int2(src | ((dst & 255) << 24), __float_as_int(ssrc[src]));
    }
  }
  __syncthreads();
#pragma unroll
  for (int q = 0; q < EPB / 512; ++q) {
    int i = q * 512 + t;
    if (i < nloc) stage[base + i] = sbuf[i];
  }
}

// ---------------- 3-pass grid-parallel exclusive scan of cnt[TOTC] --------------
__global__ __launch_bounds__(256) void k_scanA(const int* __restrict__ cnt,
                                               int* __restrict__ partials)
{
  __shared__ int sm[256];
  int t = threadIdx.x, b = blockIdx.x;
  const int4* c4 = (const int4*)(cnt + b * SBLK + t * 8);
  int4 u = c4[0], v = c4[1];
  sm[t] = u.x + u.y + u.z + u.w + v.x + v.y + v.z + v.w;
  __syncthreads();
  for (int s = 128; s > 0; s >>= 1) { if (t < s) sm[t] += sm[t + s]; __syncthreads(); }
  if (t == 0) partials[b] = sm[0];
}

__global__ __launch_bounds__(256) void k_scanB(int* __restrict__ partials,
                                               int* __restrict__ boff,
                                               int* __restrict__ offsets)
{
  __shared__ int sm[256];
  int t = threadIdx.x;
  int v = (t < NSB) ? partials[t] : 0;
  sm[t] = v;
  __syncthreads();
  for (int off = 1; off < 256; off <<= 1) {
    int u = (t >= off) ? sm[t - off] : 0;
    __syncthreads();
    sm[t] += u;
    __syncthreads();
  }
  if (t < NSB) partials[t] = sm[t] - v;   // exclusive
  if (t == 0) { boff[NBKT] = NE; offsets[NN] = NE; }
}

__global__ __launch_bounds__(256) void k_scanC(int* __restrict__ cnt,
                                               const int* __restrict__ partials,
                                               int* __restrict__ boff)
{
  __shared__ int sm[256];
  int t = threadIdx.x, b = blockIdx.x;
  int base = b * SBLK + t * 8;
  int4* c4 = (int4*)(cnt + base);
  int4 u = c4[0], v = c4[1];
  int tot = u.x + u.y + u.z + u.w + v.x + v.y + v.z + v.w;
  sm[t] = tot;
  __syncthreads();
  for (int off = 1; off < 256; off <<= 1) {
    int w = (t >= off) ? sm[t - off] : 0;
    __syncthreads();
    sm[t] += w;
    __syncthreads();
  }
  int run = partials[b] + sm[t] - tot;
  int e[8] = {u.x, u.y, u.z, u.w, v.x, v.y, v.z, v.w};
  int ex[8];
#pragma unroll
  for (int k = 0; k < 8; ++k) { ex[k] = run; run += e[k]; }
#pragma unroll
  for (int k = 0; k < 8; ++k) {
    int idx = base + k;
    if (idx < TOTC && idx % NPB == 0) boff[idx / NPB] = ex[k];
  }
  c4[0] = make_int4(ex[0], ex[1], ex[2], ex[3]);
  c4[1] = make_int4(ex[4], ex[5], ex[6], ex[7]);
}

// ---------------- k_place: gather bucket runs (512 thr), node-sort, CSR ---------
__global__ __launch_bounds__(512) void k_place(const int* __restrict__ boff,
                                               const int* __restrict__ cnt,   // post-scan outpos
                                               const int* __restrict__ lpre,
                                               const int2* __restrict__ stage,
                                               const float* __restrict__ sdst,
                                               int* __restrict__ offsets,
                                               int2* __restrict__ csr)
{
  __shared__ int2 lbuf[LBUF];   // 48KB
  __shared__ int nh[256];
  __shared__ int cur[256];
  __shared__ float sdl[256];
  const int b = blockIdx.x, t = threadIdx.x;
  const int e_beg = boff[b], e_end = boff[b + 1];
  const int m = e_end - e_beg;

  for (int c = t; c < NPB; c += 512) {
    int lp = lpre[c * LPS + b];
    int lq = lpre[c * LPS + b + 1];
    int outp = cnt[b * NPB + c] - e_beg;
    int sin = c * EPB + lp;
    for (int k = 0; k < lq - lp; ++k) lbuf[outp + k] = stage[sin + k];
  }
  if (t < 256) {
    nh[t] = 0;
    int node = (b << 8) + t;
    sdl[t] = (node < NN) ? sdst[node] : 0.f;
  }
  __syncthreads();

  for (int i = t; i < m; i += 512)
    atomicAdd(&nh[((uint)lbuf[i].x) >> 24], 1);
  __syncthreads();
  int v0 = (t < 256) ? nh[t] : 0;
  for (int off = 1; off < 256; off <<= 1) {
    int u = (t >= off && t < 256) ? nh[t - off] : 0;
    __syncthreads();
    if (t < 256) nh[t] += u;
    __syncthreads();
  }
  if (t < 256) {
    int excl = nh[t] - v0;
    cur[t] = excl;
    int node = (b << 8) + t;
    if (node < NN) offsets[node] = e_beg + excl;
  }
  __syncthreads();

  for (int i = t; i < m; i += 512) {
    int2 v = lbuf[i];
    int dl = ((uint)v.x) >> 24;
    int slot = atomicAdd(&cur[dl], 1);
    float e = __int_as_float(v.y) + sdl[dl];
    e = (e >= 0.f) ? e : 0.2f * e;           // LeakyReLU(0.2)
    e = fminf(fmaxf(e, -10.f), 10.f);        // clip
    csr[e_beg + slot] = make_int2(v.x & 0xFFFFFF, __float_as_int(__expf(e)));
  }
}

// ---------------- aggregation: 16 lanes/node, uint4 gathers, unroll-8 -----------
// lane = (half, dim-octet): 16 lanes x 16B = 2 h rows per load instruction.
// unroll-8 pairs -> 16 edges/iter, 8 independent 16B gathers in flight/lane.
__global__ __launch_bounds__(256) void k_agg(const int* __restrict__ offsets,
                                             const int2* __restrict__ csr,
                                             const ushort* __restrict__ h16,
                                             float* __restrict__ out)
{
  int t = blockIdx.x * 256 + threadIdx.x;
  int node = t >> 4;
  if (node >= NN) return;
  int l16 = t & 15;
  int half = l16 >> 3;       // which edge of each pair
  int l8 = l16 & 7;          // dim octet (8 bf16 = 16B)
  int beg = offsets[node];
  int end = offsets[node + 1];
  const uint4* h4 = (const uint4*)h16;
  float a0 = 0.f, a1 = 0.f, a2 = 0.f, a3 = 0.f;
  float a4 = 0.f, a5 = 0.f, a6 = 0.f, a7 = 0.f;
  float den = 0.f;
  int last = end - 1;
  for (int j = beg; j < end; j += 16) {
#pragma unroll
    for (int p = 0; p < 8; ++p) {
      int idx = j + p * 2 + half;
      int2 e = csr[min(idx, last)];
      float a = (idx < end) ? __int_as_float(e.y) : 0.f;
      uint4 hq = h4[(size_t)e.x * 8 + l8];
      den += a;
      a0 += a * bf2f((ushort)(hq.x & 0xffff));
      a1 += a * bf2f((ushort)(hq.x >> 16));
      a2 += a * bf2f((ushort)(hq.y & 0xffff));
      a3 += a * bf2f((ushort)(hq.y >> 16));
      a4 += a * bf2f((ushort)(hq.z & 0xffff));
      a5 += a * bf2f((ushort)(hq.z >> 16));
      a6 += a * bf2f((ushort)(hq.w & 0xffff));
      a7 += a * bf2f((ushort)(hq.w >> 16));
    }
  }
  // combine the two edge-halves (lanes l and l^8 hold the same dims)
  a0 += __shfl_xor(a0, 8);
  a1 += __shfl_xor(a1, 8);
  a2 += __shfl_xor(a2, 8);
  a3 += __shfl_xor(a3, 8);
  a4 += __shfl_xor(a4, 8);
  a5 += __shfl_xor(a5, 8);
  a6 += __shfl_xor(a6, 8);
  a7 += __shfl_xor(a7, 8);
  den += __shfl_xor(den, 8);
  float inv = 1.f / (den + 1e-9f);
  float4 o = half ? make_float4(a4 * inv, a5 * inv, a6 * inv, a7 * inv)
                  : make_float4(a0 * inv, a1 * inv, a2 * inv, a3 * inv);
  ((float4*)out)[(size_t)node * 16 + l8 * 2 + half] = o;
}

extern "C" void kernel_launch(void* const* d_in, const int* in_sizes, int n_in,
                              void* d_out, int out_size, void* d_ws, size_t ws_size,
                              hipStream_t stream)
{
  const float* x     = (const float*)d_in[0];
  const int*   ei    = (const int*)d_in[1];
  const float* W     = (const float*)d_in[2];
  const float* a_src = (const float*)d_in[3];
  const float* a_dst = (const float*)d_in[4];
  float* out = (float*)d_out;

  char* p = (char*)d_ws;
  auto alloc = [&](size_t bytes) -> char* {
    char* r = p;
    p += (bytes + 255) & ~(size_t)255;
    return r;
  };
  ushort* h16    = (ushort*)alloc((size_t)NN * 64 * 2);
  float* ssrc    = (float*)alloc((size_t)NN * 4);
  float* sdst    = (float*)alloc((size_t)NN * 4);
  int*   offsets = (int*)alloc((size_t)(NN + 1) * 4);
  int*   cnt     = (int*)alloc((size_t)NSB * SBLK * 4);   // padded past TOTC
  int*   lpre    = (int*)alloc((size_t)NPB * LPS * 4);
  int*   boff    = (int*)alloc((size_t)(NBKT + 1) * 4);
  int*   partials= (int*)alloc((size_t)NSB * 4);
  int2*  stage   = (int2*)alloc((size_t)NPB * EPB * 8);
  int2*  csr     = (int2*)alloc((size_t)NE * 8);

  k_h<<<(NN + 63) / 64, 256, 0, stream>>>(x, W, a_src, a_dst, h16, ssrc, sdst);
  k_sort<<<NPB, 512, 0, stream>>>(ei, ssrc, cnt, lpre, stage);
  k_scanA<<<NSB, 256, 0, stream>>>(cnt, partials);
  k_scanB<<<1, 256, 0, stream>>>(partials, boff, offsets);
  k_scanC<<<NSB, 256, 0, stream>>>(cnt, partials, boff);
  k_place<<<NBKT, 512, 0, stream>>>(boff, cnt, lpre, stage, sdst, offsets, csr);
  k_agg<<<((size_t)NN * 16 + 255) / 256, 256, 0, stream>>>(offsets, csr, h16, out);
}

// Round 12
// 95.761 us; speedup vs baseline: 1.1014x; 1.1014x over previous
//
#include <hip/hip_runtime.h>
#include <math.h>

#define NN 100000          // nodes
#define NE 1600000         // edges
#define BKB 7              // bucket bits -> 128 nodes/bucket
#define BSZ 128            // nodes per bucket
#define NBKT 782           // ceil(NN/128)
#define LPS  (NBKT + 1)    // lpre row stride (chunk-major)
#define EPB 2048           // edges per sort chunk
#define NPB ((NE + EPB - 1) / EPB)        // 782 chunks
#define TOTC (NBKT * NPB)                 // 611,524 cells (bucket-major)
#define SBLK 2048                         // scan elems per block
#define NSB ((TOTC + SBLK - 1) / SBLK)    // 299 scan blocks
#define LBUF2 2560         // per-bucket LDS entry cap (mean 2046, +11 sigma)
#define EVC 5              // LBUF2 / 512

typedef unsigned int uint;
typedef unsigned short ushort;
typedef __attribute__((ext_vector_type(8))) short bfx8;
typedef __attribute__((ext_vector_type(4))) float f32x4;

static __device__ __forceinline__ ushort f2bf(float f) {
  uint u = __float_as_uint(f);
  uint r = (u + 0x7fffu + ((u >> 16) & 1u)) >> 16;   // RNE
  return (ushort)r;
}
static __device__ __forceinline__ float bf2f(ushort v) {
  return __uint_as_float((uint)v << 16);
}
static __device__ __forceinline__ bfx8 cvt8(float4 a, float4 b) {
  bfx8 r;
  r[0] = (short)f2bf(a.x); r[1] = (short)f2bf(a.y);
  r[2] = (short)f2bf(a.z); r[3] = (short)f2bf(a.w);
  r[4] = (short)f2bf(b.x); r[5] = (short)f2bf(b.y);
  r[6] = (short)f2bf(b.z); r[7] = (short)f2bf(b.w);
  return r;
}

// ---------------- Kernel A: h = x @ W^T via bf16 MFMA, fused s_src/s_dst ----
__global__ __launch_bounds__(256) void k_h(
    const float* __restrict__ x, const float* __restrict__ W,
    const float* __restrict__ a_src, const float* __restrict__ a_dst,
    ushort* __restrict__ h16, float* __restrict__ ssrc, float* __restrict__ sdst)
{
  __shared__ __align__(16) ushort ws[64 * 128];   // 16KB
  const int t = threadIdx.x;
  const int base = blockIdx.x * 64;
  const float4* x4 = (const float4*)x;
  const float4* W4 = (const float4*)W;

#pragma unroll
  for (int q = 0; q < 8; ++q) {
    int f = q * 256 + t;
    int row = f >> 5, c4 = f & 31;
    float4 v = W4[f];
    ushort4 pk = make_ushort4(f2bf(v.x), f2bf(v.y), f2bf(v.z), f2bf(v.w));
    int byte = row * 256 + ((c4 * 8) ^ ((row & 7) << 4));
    *(ushort4*)((char*)ws + byte) = pk;
  }

  const int wid = t >> 6;
  const int lane = t & 63;
  const int lg = lane >> 4;
  const int lr = lane & 15;

  const int node = base + wid * 16 + lr;
  const bool ok = node < NN;
  const float4* xr = x4 + (size_t)node * 32;

  float4 xa[4][2];
#pragma unroll
  for (int ks = 0; ks < 4; ++ks) {
    xa[ks][0] = ok ? xr[ks * 8 + lg * 2]     : make_float4(0.f, 0.f, 0.f, 0.f);
    xa[ks][1] = ok ? xr[ks * 8 + lg * 2 + 1] : make_float4(0.f, 0.f, 0.f, 0.f);
  }
  __syncthreads();

  f32x4 acc[4];
#pragma unroll
  for (int ng = 0; ng < 4; ++ng) acc[ng] = (f32x4){0.f, 0.f, 0.f, 0.f};

#pragma unroll
  for (int ks = 0; ks < 4; ++ks) {
    int kb = ks * 64 + lg * 16;
    bfx8 af = cvt8(xa[ks][0], xa[ks][1]);
    bfx8 bfr[4];
#pragma unroll
    for (int ng = 0; ng < 4; ++ng) {
      int row = ng * 16 + lr;
      bfr[ng] = *(const bfx8*)((const char*)ws + row * 256 + (kb ^ ((row & 7) << 4)));
    }
#pragma unroll
    for (int ng = 0; ng < 4; ++ng)
      acc[ng] = __builtin_amdgcn_mfma_f32_16x16x32_bf16(af, bfr[ng], acc[ng], 0, 0, 0);
  }

  float as_[4], ad_[4];
#pragma unroll
  for (int ng = 0; ng < 4; ++ng) { as_[ng] = a_src[ng * 16 + lr]; ad_[ng] = a_dst[ng * 16 + lr]; }
#pragma unroll
  for (int r = 0; r < 4; ++r) {
    int nout = base + wid * 16 + lg * 4 + r;
    float ps = 0.f, pd = 0.f;
#pragma unroll
    for (int ng = 0; ng < 4; ++ng) { ps += acc[ng][r] * as_[ng]; pd += acc[ng][r] * ad_[ng]; }
#pragma unroll
    for (int m = 1; m < 16; m <<= 1) { ps += __shfl_xor(ps, m); pd += __shfl_xor(pd, m); }
    if (lr == 0 && nout < NN) { ssrc[nout] = ps; sdst[nout] = pd; }
    if (nout < NN) {
#pragma unroll
      for (int ng = 0; ng < 4; ++ng)
        h16[(size_t)nout * 64 + ng * 16 + lr] = f2bf(acc[ng][r]);
    }
  }
}

// ---------------- k_sort: per-chunk bucket sort in LDS, coalesced outputs -------
// stage[c*EPB+i]: sorted-by-bucket {src | dl<<24, ssrc bits}; lpre chunk-major;
// cnt_cm chunk-major counts (coalesced write; transposed later).
__global__ __launch_bounds__(512) void k_sort(const int* __restrict__ ei,
                                              const float* __restrict__ ssrc,
                                              int* __restrict__ cnt_cm,
                                              int* __restrict__ lpre,
                                              int2* __restrict__ stage)
{
  __shared__ int hh[NBKT];
  __shared__ int sums[512];
  __shared__ int2 sbuf[EPB];    // 16KB
  const int t = threadIdx.x, c = blockIdx.x;
  for (int i = t; i < NBKT; i += 512) hh[i] = 0;
  __syncthreads();

  const int base = c * EPB;
  const int nloc = min(EPB, NE - base);
  int my_src[EPB / 512], my_dst[EPB / 512];
#pragma unroll
  for (int q = 0; q < EPB / 512; ++q) {
    int e = base + q * 512 + t;
    if (e < NE) {
      my_src[q] = ei[e];
      my_dst[q] = ei[NE + e];
      atomicAdd(&hh[my_dst[q] >> BKB], 1);
    } else my_dst[q] = -1;
  }
  __syncthreads();

  // exclusive scan of hh[NBKT], 2 elems/thread
  int i0 = 2 * t, i1 = 2 * t + 1;
  int v0 = (i0 < NBKT) ? hh[i0] : 0;
  int v1 = (i1 < NBKT) ? hh[i1] : 0;
  sums[t] = v0 + v1;
  __syncthreads();
  for (int off = 1; off < 512; off <<= 1) {
    int u = (t >= off) ? sums[t - off] : 0;
    __syncthreads();
    sums[t] += u;
    __syncthreads();
  }
  int ex0 = sums[t] - (v0 + v1);
  if (i0 < NBKT) {
    hh[i0] = ex0;
    lpre[c * LPS + i0] = ex0;
    cnt_cm[(size_t)c * NBKT + i0] = v0;
  }
  if (i1 < NBKT) {
    hh[i1] = ex0 + v0;
    lpre[c * LPS + i1] = ex0 + v0;
    cnt_cm[(size_t)c * NBKT + i1] = v1;
  }
  if (t == 0) lpre[c * LPS + NBKT] = nloc;
  __syncthreads();

#pragma unroll
  for (int q = 0; q < EPB / 512; ++q) {
    if (my_dst[q] >= 0) {
      int dst = my_dst[q], src = my_src[q];
      int pos = atomicAdd(&hh[dst >> BKB], 1);
      sbuf[pos] = make_int2(src | ((dst & (BSZ - 1)) << 24), __float_as_int(ssrc[src]));
    }
  }
  __syncthreads();
#pragma unroll
  for (int q = 0; q < EPB / 512; ++q) {
    int i = q * 512 + t;
    if (i < nloc) stage[base + i] = sbuf[i];
  }
}

// ---------------- k_tr: transpose cnt_cm[c][b] -> cnt[b][c] (both coalesced) ----
__global__ __launch_bounds__(256) void k_tr(const int* __restrict__ cnt_cm,
                                            int* __restrict__ cnt)
{
  __shared__ int tile[32][33];
  int cb = blockIdx.x * 32, bb = blockIdx.y * 32;
  int tx = threadIdx.x & 31, ty = threadIdx.x >> 5;   // 32x8
  for (int r = ty; r < 32; r += 8) {
    int c = cb + r, b = bb + tx;
    tile[r][tx] = (c < NPB && b < NBKT) ? cnt_cm[(size_t)c * NBKT + b] : 0;
  }
  __syncthreads();
  for (int r = ty; r < 32; r += 8) {
    int b = bb + r, c = cb + tx;
    if (b < NBKT && c < NPB) cnt[(size_t)b * NPB + c] = tile[tx][r];
  }
}

// ---------------- 3-pass grid-parallel exclusive scan of cnt[TOTC] --------------
__global__ __launch_bounds__(256) void k_scanA(const int* __restrict__ cnt,
                                               int* __restrict__ partials)
{
  __shared__ int sm[256];
  int t = threadIdx.x, b = blockIdx.x;
  const int4* c4 = (const int4*)(cnt + b * SBLK + t * 8);
  int4 u = c4[0], v = c4[1];
  sm[t] = u.x + u.y + u.z + u.w + v.x + v.y + v.z + v.w;
  __syncthreads();
  for (int s = 128; s > 0; s >>= 1) { if (t < s) sm[t] += sm[t + s]; __syncthreads(); }
  if (t == 0) partials[b] = sm[0];
}

__global__ __launch_bounds__(512) void k_scanB(int* __restrict__ partials,
                                               int* __restrict__ boff)
{
  __shared__ int sm[512];
  int t = threadIdx.x;
  int v = (t < NSB) ? partials[t] : 0;
  sm[t] = v;
  __syncthreads();
  for (int off = 1; off < 512; off <<= 1) {
    int u = (t >= off) ? sm[t - off] : 0;
    __syncthreads();
    sm[t] += u;
    __syncthreads();
  }
  if (t < NSB) partials[t] = sm[t] - v;   // exclusive
  if (t == 0) boff[NBKT] = NE;
}

__global__ __launch_bounds__(256) void k_scanC(int* __restrict__ cnt,
                                               const int* __restrict__ partials,
                                               int* __restrict__ boff)
{
  __shared__ int sm[256];
  int t = threadIdx.x, b = blockIdx.x;
  int base = b * SBLK + t * 8;
  int4* c4 = (int4*)(cnt + base);
  int4 u = c4[0], v = c4[1];
  int tot = u.x + u.y + u.z + u.w + v.x + v.y + v.z + v.w;
  sm[t] = tot;
  __syncthreads();
  for (int off = 1; off < 256; off <<= 1) {
    int w = (t >= off) ? sm[t - off] : 0;
    __syncthreads();
    sm[t] += w;
    __syncthreads();
  }
  int run = partials[b] + sm[t] - tot;
  int e[8] = {u.x, u.y, u.z, u.w, v.x, v.y, v.z, v.w};
  int ex[8];
#pragma unroll
  for (int k = 0; k < 8; ++k) { ex[k] = run; run += e[k]; }
#pragma unroll
  for (int k = 0; k < 8; ++k) {
    int idx = base + k;
    if (idx < TOTC && idx % NPB == 0) boff[idx / NPB] = ex[k];
  }
  c4[0] = make_int4(ex[0], ex[1], ex[2], ex[3]);
  c4[1] = make_int4(ex[4], ex[5], ex[6], ex[7]);
}

// ---------------- k_fuse: gather runs -> LDS node-sort -> aggregate -> out ------
// Replaces k_place + k_agg: CSR never goes to global memory.
__global__ __launch_bounds__(512) void k_fuse(const int* __restrict__ boff,
                                              const int* __restrict__ pcnt,  // scanned cnt
                                              const int* __restrict__ lpre,
                                              const int2* __restrict__ stage,
                                              const float* __restrict__ sdst,
                                              const ushort* __restrict__ h16,
                                              float* __restrict__ out)
{
  __shared__ int2 lbuf[LBUF2];    // 20KB
  __shared__ int nh[BSZ];         // hist, then pristine node starts
  __shared__ int nst[BSZ];        // inclusive scan (node ends)
  __shared__ int cur[BSZ];        // mutable cursors
  __shared__ float sdl[BSZ];
  const int b = blockIdx.x, t = threadIdx.x;
  const int e_beg = boff[b], e_end = boff[b + 1];
  const int m = e_end - e_beg;

  // phase 1: gather this bucket's runs from all chunks
  for (int c = t; c < NPB; c += 512) {
    int lp = lpre[c * LPS + b];
    int lq = lpre[c * LPS + b + 1];
    int outp = pcnt[(size_t)b * NPB + c] - e_beg;
    int sin = c * EPB + lp;
    for (int k = 0; k < lq - lp; ++k) lbuf[outp + k] = stage[sin + k];
  }
  if (t < BSZ) {
    nh[t] = 0;
    int node = (b << BKB) + t;
    sdl[t] = (node < NN) ? sdst[node] : 0.f;
  }
  __syncthreads();

  // phase 2: cache entries in regs + node histogram
  int2 ev[EVC];
  int ne = 0;
#pragma unroll
  for (int q = 0; q < EVC; ++q) {
    int i = q * 512 + t;
    if (i < m) { ev[q] = lbuf[i]; atomicAdd(&nh[((uint)ev[q].x) >> 24], 1); ne = q + 1; }
  }
  __syncthreads();
  int v0 = (t < BSZ) ? nh[t] : 0;
  if (t < BSZ) nst[t] = v0;
  __syncthreads();
  for (int off = 1; off < BSZ; off <<= 1) {
    int u = (t >= off && t < BSZ) ? nst[t - off] : 0;
    __syncthreads();
    if (t < BSZ) nst[t] += u;
    __syncthreads();
  }
  if (t < BSZ) { int ex = nst[t] - v0; cur[t] = ex; nh[t] = ex; }  // nh = pristine starts
  __syncthreads();

  // phase 3: in-place permute into node-sorted order, alpha computed here
  int slots[EVC];
  float alph[EVC];
#pragma unroll
  for (int q = 0; q < EVC; ++q) {
    if (q < ne) {
      int dl = ((uint)ev[q].x) >> 24;
      slots[q] = atomicAdd(&cur[dl], 1);
      float e = __int_as_float(ev[q].y) + sdl[dl];
      e = (e >= 0.f) ? e : 0.2f * e;           // LeakyReLU(0.2)
      e = fminf(fmaxf(e, -10.f), 10.f);        // clip
      alph[q] = __expf(e);
    }
  }
  __syncthreads();
#pragma unroll
  for (int q = 0; q < EVC; ++q)
    if (q < ne) lbuf[slots[q]] = make_int2(ev[q].x & 0xFFFFFF, __float_as_int(alph[q]));
  __syncthreads();

  // phase 4: aggregation — 32 streams x 16 lanes, 4 nodes/stream, uint4 gathers
  const int sid = t >> 4;
  const int l16 = t & 15;
  const int half = l16 >> 3, l8 = l16 & 7;
  const uint4* h4 = (const uint4*)h16;
#pragma unroll
  for (int r = 0; r < 4; ++r) {
    int nl = sid + 32 * r;
    int beg = nh[nl];
    int end = nst[nl];
    float a0 = 0.f, a1 = 0.f, a2 = 0.f, a3 = 0.f;
    float a4 = 0.f, a5 = 0.f, a6 = 0.f, a7 = 0.f;
    float den = 0.f;
    int last = end - 1;
    for (int j = beg; j < end; j += 8) {
#pragma unroll
      for (int p = 0; p < 4; ++p) {
        int idx = j + p * 2 + half;
        int2 e = lbuf[min(idx, last)];
        float a = (idx < end) ? __int_as_float(e.y) : 0.f;
        uint4 hq = h4[(size_t)e.x * 8 + l8];
        den += a;
        a0 += a * bf2f((ushort)(hq.x & 0xffff));
        a1 += a * bf2f((ushort)(hq.x >> 16));
        a2 += a * bf2f((ushort)(hq.y & 0xffff));
        a3 += a * bf2f((ushort)(hq.y >> 16));
        a4 += a * bf2f((ushort)(hq.z & 0xffff));
        a5 += a * bf2f((ushort)(hq.z >> 16));
        a6 += a * bf2f((ushort)(hq.w & 0xffff));
        a7 += a * bf2f((ushort)(hq.w >> 16));
      }
    }
    a0 += __shfl_xor(a0, 8);
    a1 += __shfl_xor(a1, 8);
    a2 += __shfl_xor(a2, 8);
    a3 += __shfl_xor(a3, 8);
    a4 += __shfl_xor(a4, 8);
    a5 += __shfl_xor(a5, 8);
    a6 += __shfl_xor(a6, 8);
    a7 += __shfl_xor(a7, 8);
    den += __shfl_xor(den, 8);
    int node = (b << BKB) + nl;
    if (node < NN) {
      float inv = 1.f / (den + 1e-9f);
      float4 o = half ? make_float4(a4 * inv, a5 * inv, a6 * inv, a7 * inv)
                      : make_float4(a0 * inv, a1 * inv, a2 * inv, a3 * inv);
      ((float4*)out)[(size_t)node * 16 + l8 * 2 + half] = o;
    }
  }
}

extern "C" void kernel_launch(void* const* d_in, const int* in_sizes, int n_in,
                              void* d_out, int out_size, void* d_ws, size_t ws_size,
                              hipStream_t stream)
{
  const float* x     = (const float*)d_in[0];
  const int*   ei    = (const int*)d_in[1];
  const float* W     = (const float*)d_in[2];
  const float* a_src = (const float*)d_in[3];
  const float* a_dst = (const float*)d_in[4];
  float* out = (float*)d_out;

  char* p = (char*)d_ws;
  auto alloc = [&](size_t bytes) -> char* {
    char* r = p;
    p += (bytes + 255) & ~(size_t)255;
    return r;
  };
  ushort* h16    = (ushort*)alloc((size_t)NN * 64 * 2);
  float* ssrc    = (float*)alloc((size_t)NN * 4);
  float* sdst    = (float*)alloc((size_t)NN * 4);
  int*   cnt     = (int*)alloc((size_t)NSB * SBLK * 4);   // padded past TOTC
  int*   cnt_cm  = (int*)alloc((size_t)NPB * NBKT * 4);
  int*   lpre    = (int*)alloc((size_t)NPB * LPS * 4);
  int*   boff    = (int*)alloc((size_t)(NBKT + 1) * 4);
  int*   partials= (int*)alloc((size_t)NSB * 4);
  int2*  stage   = (int2*)alloc((size_t)NPB * EPB * 8);

  k_h<<<(NN + 63) / 64, 256, 0, stream>>>(x, W, a_src, a_dst, h16, ssrc, sdst);
  k_sort<<<NPB, 512, 0, stream>>>(ei, ssrc, cnt_cm, lpre, stage);
  k_tr<<<dim3((NPB + 31) / 32, (NBKT + 31) / 32), 256, 0, stream>>>(cnt_cm, cnt);
  k_scanA<<<NSB, 256, 0, stream>>>(cnt, partials);
  k_scanB<<<1, 512, 0, stream>>>(partials, boff);
  k_scanC<<<NSB, 256, 0, stream>>>(cnt, partials, boff);
  k_fuse<<<NBKT, 512, 0, stream>>>(boff, cnt, lpre, stage, sdst, h16, out);
}

// Round 13
// 89.926 us; speedup vs baseline: 1.1728x; 1.0649x over previous
//
#include <hip/hip_runtime.h>
#include <math.h>

#define NN 100000          // nodes
#define NE 1600000         // edges
#define BKB 7              // bucket bits -> 128 nodes/bucket
#define BSZ 128            // nodes per bucket
#define NBKT 782           // ceil(NN/128)
#define LPS  (NBKT + 1)    // lpre row stride (chunk-major)
#define EPB 2048           // edges per sort chunk
#define NPB ((NE + EPB - 1) / EPB)        // 782 chunks
#define TOTC (NBKT * NPB)                 // 611,524 cells (bucket-major)
#define SBLK 2048                         // scan elems per block
#define NSB ((TOTC + SBLK - 1) / SBLK)    // 299 scan blocks
#define LBUF2 2560         // per-bucket LDS entry cap (mean 2046, +11 sigma)
#define EVC 5              // LBUF2 / 512

typedef unsigned int uint;
typedef unsigned short ushort;
typedef __attribute__((ext_vector_type(8))) short bfx8;
typedef __attribute__((ext_vector_type(4))) float f32x4;

static __device__ __forceinline__ ushort f2bf(float f) {
  uint u = __float_as_uint(f);
  uint r = (u + 0x7fffu + ((u >> 16) & 1u)) >> 16;   // RNE
  return (ushort)r;
}
static __device__ __forceinline__ float bf2f(ushort v) {
  return __uint_as_float((uint)v << 16);
}
static __device__ __forceinline__ bfx8 cvt8(float4 a, float4 b) {
  bfx8 r;
  r[0] = (short)f2bf(a.x); r[1] = (short)f2bf(a.y);
  r[2] = (short)f2bf(a.z); r[3] = (short)f2bf(a.w);
  r[4] = (short)f2bf(b.x); r[5] = (short)f2bf(b.y);
  r[6] = (short)f2bf(b.z); r[7] = (short)f2bf(b.w);
  return r;
}

// ---------------- Kernel A: h = x @ W^T via bf16 MFMA, fused s_src/s_dst ----
__global__ __launch_bounds__(256) void k_h(
    const float* __restrict__ x, const float* __restrict__ W,
    const float* __restrict__ a_src, const float* __restrict__ a_dst,
    ushort* __restrict__ h16, float* __restrict__ ssrc, float* __restrict__ sdst)
{
  __shared__ __align__(16) ushort ws[64 * 128];   // 16KB
  const int t = threadIdx.x;
  const int base = blockIdx.x * 64;
  const float4* x4 = (const float4*)x;
  const float4* W4 = (const float4*)W;

#pragma unroll
  for (int q = 0; q < 8; ++q) {
    int f = q * 256 + t;
    int row = f >> 5, c4 = f & 31;
    float4 v = W4[f];
    ushort4 pk = make_ushort4(f2bf(v.x), f2bf(v.y), f2bf(v.z), f2bf(v.w));
    int byte = row * 256 + ((c4 * 8) ^ ((row & 7) << 4));
    *(ushort4*)((char*)ws + byte) = pk;
  }

  const int wid = t >> 6;
  const int lane = t & 63;
  const int lg = lane >> 4;
  const int lr = lane & 15;

  const int node = base + wid * 16 + lr;
  const bool ok = node < NN;
  const float4* xr = x4 + (size_t)node * 32;

  float4 xa[4][2];
#pragma unroll
  for (int ks = 0; ks < 4; ++ks) {
    xa[ks][0] = ok ? xr[ks * 8 + lg * 2]     : make_float4(0.f, 0.f, 0.f, 0.f);
    xa[ks][1] = ok ? xr[ks * 8 + lg * 2 + 1] : make_float4(0.f, 0.f, 0.f, 0.f);
  }
  __syncthreads();

  f32x4 acc[4];
#pragma unroll
  for (int ng = 0; ng < 4; ++ng) acc[ng] = (f32x4){0.f, 0.f, 0.f, 0.f};

#pragma unroll
  for (int ks = 0; ks < 4; ++ks) {
    int kb = ks * 64 + lg * 16;
    bfx8 af = cvt8(xa[ks][0], xa[ks][1]);
    bfx8 bfr[4];
#pragma unroll
    for (int ng = 0; ng < 4; ++ng) {
      int row = ng * 16 + lr;
      bfr[ng] = *(const bfx8*)((const char*)ws + row * 256 + (kb ^ ((row & 7) << 4)));
    }
#pragma unroll
    for (int ng = 0; ng < 4; ++ng)
      acc[ng] = __builtin_amdgcn_mfma_f32_16x16x32_bf16(af, bfr[ng], acc[ng], 0, 0, 0);
  }

  float as_[4], ad_[4];
#pragma unroll
  for (int ng = 0; ng < 4; ++ng) { as_[ng] = a_src[ng * 16 + lr]; ad_[ng] = a_dst[ng * 16 + lr]; }
#pragma unroll
  for (int r = 0; r < 4; ++r) {
    int nout = base + wid * 16 + lg * 4 + r;
    float ps = 0.f, pd = 0.f;
#pragma unroll
    for (int ng = 0; ng < 4; ++ng) { ps += acc[ng][r] * as_[ng]; pd += acc[ng][r] * ad_[ng]; }
#pragma unroll
    for (int m = 1; m < 16; m <<= 1) { ps += __shfl_xor(ps, m); pd += __shfl_xor(pd, m); }
    if (lr == 0 && nout < NN) { ssrc[nout] = ps; sdst[nout] = pd; }
    if (nout < NN) {
#pragma unroll
      for (int ng = 0; ng < 4; ++ng)
        h16[(size_t)nout * 64 + ng * 16 + lr] = f2bf(acc[ng][r]);
    }
  }
}

// ---------------- k_sort: per-chunk bucket sort in LDS, coalesced outputs -------
__global__ __launch_bounds__(512) void k_sort(const int* __restrict__ ei,
                                              const float* __restrict__ ssrc,
                                              int* __restrict__ cnt_cm,
                                              int* __restrict__ lpre,
                                              int2* __restrict__ stage)
{
  __shared__ int hh[NBKT];
  __shared__ int sums[512];
  __shared__ int2 sbuf[EPB];    // 16KB
  const int t = threadIdx.x, c = blockIdx.x;
  for (int i = t; i < NBKT; i += 512) hh[i] = 0;
  __syncthreads();

  const int base = c * EPB;
  const int nloc = min(EPB, NE - base);
  int my_src[EPB / 512], my_dst[EPB / 512];
#pragma unroll
  for (int q = 0; q < EPB / 512; ++q) {
    int e = base + q * 512 + t;
    if (e < NE) {
      my_src[q] = ei[e];
      my_dst[q] = ei[NE + e];
      atomicAdd(&hh[my_dst[q] >> BKB], 1);
    } else my_dst[q] = -1;
  }
  __syncthreads();

  // exclusive scan of hh[NBKT], 2 elems/thread
  int i0 = 2 * t, i1 = 2 * t + 1;
  int v0 = (i0 < NBKT) ? hh[i0] : 0;
  int v1 = (i1 < NBKT) ? hh[i1] : 0;
  sums[t] = v0 + v1;
  __syncthreads();
  for (int off = 1; off < 512; off <<= 1) {
    int u = (t >= off) ? sums[t - off] : 0;
    __syncthreads();
    sums[t] += u;
    __syncthreads();
  }
  int ex0 = sums[t] - (v0 + v1);
  if (i0 < NBKT) {
    hh[i0] = ex0;
    lpre[c * LPS + i0] = ex0;
    cnt_cm[(size_t)c * NBKT + i0] = v0;
  }
  if (i1 < NBKT) {
    hh[i1] = ex0 + v0;
    lpre[c * LPS + i1] = ex0 + v0;
    cnt_cm[(size_t)c * NBKT + i1] = v1;
  }
  if (t == 0) lpre[c * LPS + NBKT] = nloc;
  __syncthreads();

#pragma unroll
  for (int q = 0; q < EPB / 512; ++q) {
    if (my_dst[q] >= 0) {
      int dst = my_dst[q], src = my_src[q];
      int pos = atomicAdd(&hh[dst >> BKB], 1);
      sbuf[pos] = make_int2(src | ((dst & (BSZ - 1)) << 24), __float_as_int(ssrc[src]));
    }
  }
  __syncthreads();
#pragma unroll
  for (int q = 0; q < EPB / 512; ++q) {
    int i = q * 512 + t;
    if (i < nloc) stage[base + i] = sbuf[i];
  }
}

// ---------------- k_tr: transpose cnt_cm and lpre to bucket-major ---------------
__global__ __launch_bounds__(256) void k_tr(const int* __restrict__ cnt_cm,
                                            const int* __restrict__ lpre,
                                            int* __restrict__ cnt,
                                            int* __restrict__ lpreT)
{
  __shared__ int tileA[32][33];
  __shared__ int tileB[32][33];
  int cb = blockIdx.x * 32, bb = blockIdx.y * 32;
  int tx = threadIdx.x & 31, ty = threadIdx.x >> 5;   // 32x8
  for (int r = ty; r < 32; r += 8) {
    int c = cb + r, b = bb + tx;
    bool in = (c < NPB && b < NBKT);
    tileA[r][tx] = in ? cnt_cm[(size_t)c * NBKT + b] : 0;
    tileB[r][tx] = in ? lpre[(size_t)c * LPS + b] : 0;
  }
  __syncthreads();
  for (int r = ty; r < 32; r += 8) {
    int b = bb + r, c = cb + tx;
    if (b < NBKT && c < NPB) {
      cnt[(size_t)b * NPB + c] = tileA[tx][r];
      lpreT[(size_t)b * NPB + c] = tileB[tx][r];
    }
  }
}

// ---------------- 3-pass grid-parallel exclusive scan of cnt[TOTC] --------------
__global__ __launch_bounds__(256) void k_scanA(const int* __restrict__ cnt,
                                               int* __restrict__ partials)
{
  __shared__ int sm[256];
  int t = threadIdx.x, b = blockIdx.x;
  const int4* c4 = (const int4*)(cnt + b * SBLK + t * 8);
  int4 u = c4[0], v = c4[1];
  sm[t] = u.x + u.y + u.z + u.w + v.x + v.y + v.z + v.w;
  __syncthreads();
  for (int s = 128; s > 0; s >>= 1) { if (t < s) sm[t] += sm[t + s]; __syncthreads(); }
  if (t == 0) partials[b] = sm[0];
}

__global__ __launch_bounds__(512) void k_scanB(int* __restrict__ partials,
                                               int* __restrict__ boff)
{
  __shared__ int sm[512];
  int t = threadIdx.x;
  int v = (t < NSB) ? partials[t] : 0;
  sm[t] = v;
  __syncthreads();
  for (int off = 1; off < 512; off <<= 1) {
    int u = (t >= off) ? sm[t - off] : 0;
    __syncthreads();
    sm[t] += u;
    __syncthreads();
  }
  if (t < NSB) partials[t] = sm[t] - v;   // exclusive
  if (t == 0) boff[NBKT] = NE;
}

__global__ __launch_bounds__(256) void k_scanC(int* __restrict__ cnt,
                                               const int* __restrict__ partials,
                                               int* __restrict__ boff)
{
  __shared__ int sm[256];
  int t = threadIdx.x, b = blockIdx.x;
  int base = b * SBLK + t * 8;
  int4* c4 = (int4*)(cnt + base);
  int4 u = c4[0], v = c4[1];
  int tot = u.x + u.y + u.z + u.w + v.x + v.y + v.z + v.w;
  sm[t] = tot;
  __syncthreads();
  for (int off = 1; off < 256; off <<= 1) {
    int w = (t >= off) ? sm[t - off] : 0;
    __syncthreads();
    sm[t] += w;
    __syncthreads();
  }
  int run = partials[b] + sm[t] - tot;
  int e[8] = {u.x, u.y, u.z, u.w, v.x, v.y, v.z, v.w};
  int ex[8];
#pragma unroll
  for (int k = 0; k < 8; ++k) { ex[k] = run; run += e[k]; }
#pragma unroll
  for (int k = 0; k < 8; ++k) {
    int idx = base + k;
    if (idx < TOTC && idx % NPB == 0) boff[idx / NPB] = ex[k];
  }
  c4[0] = make_int4(ex[0], ex[1], ex[2], ex[3]);
  c4[1] = make_int4(ex[4], ex[5], ex[6], ex[7]);
}

// ---------------- k_fuse: binary-search gather -> LDS node-sort -> aggregate ----
__global__ __launch_bounds__(512) void k_fuse(const int* __restrict__ boff,
                                              const int* __restrict__ pcnt,  // scanned cnt
                                              const int* __restrict__ lpreT,
                                              const int2* __restrict__ stage,
                                              const float* __restrict__ sdst,
                                              const ushort* __restrict__ h16,
                                              float* __restrict__ out)
{
  __shared__ int2 lbuf[LBUF2];    // 20KB (node-sorted entries only)
  __shared__ int pcl[NPB + 1];    // run starts (rel), ascending
  __shared__ int lpb[NPB];        // within-chunk run starts
  __shared__ int nh[BSZ];         // hist -> pristine node starts
  __shared__ int nst[BSZ];        // inclusive scan (node ends)
  __shared__ int cur[BSZ];        // mutable cursors
  __shared__ float sdl[BSZ];
  const int b = blockIdx.x, t = threadIdx.x;
  const int e_beg = boff[b], e_end = boff[b + 1];
  const int m = e_end - e_beg;

  // phase 0: stage tables (coalesced rows), init hist
  for (int j = t; j < NPB; j += 512) {
    pcl[j] = pcnt[(size_t)b * NPB + j] - e_beg;
    lpb[j] = lpreT[(size_t)b * NPB + j];
  }
  if (t == 0) pcl[NPB] = m;
  if (t < BSZ) {
    nh[t] = 0;
    int node = (b << BKB) + t;
    sdl[t] = (node < NN) ? sdst[node] : 0.f;
  }
  __syncthreads();

  // phase 1: per-entry binary search -> direct global->reg loads (independent)
  int2 ev[EVC];
  int ne = 0;
#pragma unroll
  for (int q = 0; q < EVC; ++q) {
    int i = q * 512 + t;
    if (i < m) {
      int lo = 0, hi = NPB;
      while (hi - lo > 1) { int mid = (lo + hi) >> 1; if (pcl[mid] <= i) lo = mid; else hi = mid; }
      ev[q] = stage[(size_t)lo * EPB + lpb[lo] + (i - pcl[lo])];
      atomicAdd(&nh[((uint)ev[q].x) >> 24], 1);
      ne = q + 1;
    }
  }
  __syncthreads();

  // phase 2: node-start scan
  int v0 = (t < BSZ) ? nh[t] : 0;
  if (t < BSZ) nst[t] = v0;
  __syncthreads();
  for (int off = 1; off < BSZ; off <<= 1) {
    int u = (t >= off && t < BSZ) ? nst[t - off] : 0;
    __syncthreads();
    if (t < BSZ) nst[t] += u;
    __syncthreads();
  }
  if (t < BSZ) { int ex = nst[t] - v0; cur[t] = ex; nh[t] = ex; }  // nh = pristine starts
  __syncthreads();

  // phase 3: permute into node-sorted lbuf, alpha computed here
  int slots[EVC];
  float alph[EVC];
#pragma unroll
  for (int q = 0; q < EVC; ++q) {
    if (q < ne) {
      int dl = ((uint)ev[q].x) >> 24;
      slots[q] = atomicAdd(&cur[dl], 1);
      float e = __int_as_float(ev[q].y) + sdl[dl];
      e = (e >= 0.f) ? e : 0.2f * e;           // LeakyReLU(0.2)
      e = fminf(fmaxf(e, -10.f), 10.f);        // clip
      alph[q] = __expf(e);
    }
  }
#pragma unroll
  for (int q = 0; q < EVC; ++q)
    if (q < ne) lbuf[slots[q]] = make_int2(ev[q].x & 0xFFFFFF, __float_as_int(alph[q]));
  __syncthreads();

  // phase 4: aggregation — 32 streams x 16 lanes, 4 nodes/stream, uint4 gathers
  const int sid = t >> 4;
  const int l16 = t & 15;
  const int half = l16 >> 3, l8 = l16 & 7;
  const uint4* h4 = (const uint4*)h16;
#pragma unroll
  for (int r = 0; r < 4; ++r) {
    int nl = sid + 32 * r;
    int beg = nh[nl];
    int end = nst[nl];
    float a0 = 0.f, a1 = 0.f, a2 = 0.f, a3 = 0.f;
    float a4 = 0.f, a5 = 0.f, a6 = 0.f, a7 = 0.f;
    float den = 0.f;
    int last = end - 1;
    for (int j = beg; j < end; j += 8) {
#pragma unroll
      for (int p = 0; p < 4; ++p) {
        int idx = j + p * 2 + half;
        int2 e = lbuf[min(idx, last)];
        float a = (idx < end) ? __int_as_float(e.y) : 0.f;
        uint4 hq = h4[(size_t)e.x * 8 + l8];
        den += a;
        a0 += a * bf2f((ushort)(hq.x & 0xffff));
        a1 += a * bf2f((ushort)(hq.x >> 16));
        a2 += a * bf2f((ushort)(hq.y & 0xffff));
        a3 += a * bf2f((ushort)(hq.y >> 16));
        a4 += a * bf2f((ushort)(hq.z & 0xffff));
        a5 += a * bf2f((ushort)(hq.z >> 16));
        a6 += a * bf2f((ushort)(hq.w & 0xffff));
        a7 += a * bf2f((ushort)(hq.w >> 16));
      }
    }
    a0 += __shfl_xor(a0, 8);
    a1 += __shfl_xor(a1, 8);
    a2 += __shfl_xor(a2, 8);
    a3 += __shfl_xor(a3, 8);
    a4 += __shfl_xor(a4, 8);
    a5 += __shfl_xor(a5, 8);
    a6 += __shfl_xor(a6, 8);
    a7 += __shfl_xor(a7, 8);
    den += __shfl_xor(den, 8);
    int node = (b << BKB) + nl;
    if (node < NN) {
      float inv = 1.f / (den + 1e-9f);
      float4 o = half ? make_float4(a4 * inv, a5 * inv, a6 * inv, a7 * inv)
                      : make_float4(a0 * inv, a1 * inv, a2 * inv, a3 * inv);
      ((float4*)out)[(size_t)node * 16 + l8 * 2 + half] = o;
    }
  }
}

extern "C" void kernel_launch(void* const* d_in, const int* in_sizes, int n_in,
                              void* d_out, int out_size, void* d_ws, size_t ws_size,
                              hipStream_t stream)
{
  const float* x     = (const float*)d_in[0];
  const int*   ei    = (const int*)d_in[1];
  const float* W     = (const float*)d_in[2];
  const float* a_src = (const float*)d_in[3];
  const float* a_dst = (const float*)d_in[4];
  float* out = (float*)d_out;

  char* p = (char*)d_ws;
  auto alloc = [&](size_t bytes) -> char* {
    char* r = p;
    p += (bytes + 255) & ~(size_t)255;
    return r;
  };
  ushort* h16    = (ushort*)alloc((size_t)NN * 64 * 2);
  float* ssrc    = (float*)alloc((size_t)NN * 4);
  float* sdst    = (float*)alloc((size_t)NN * 4);
  int*   cnt     = (int*)alloc((size_t)NSB * SBLK * 4);   // padded past TOTC
  int*   cnt_cm  = (int*)alloc((size_t)NPB * NBKT * 4);
  int*   lpre    = (int*)alloc((size_t)NPB * LPS * 4);
  int*   lpreT   = (int*)alloc((size_t)NBKT * NPB * 4);
  int*   boff    = (int*)alloc((size_t)(NBKT + 1) * 4);
  int*   partials= (int*)alloc((size_t)NSB * 4);
  int2*  stage   = (int2*)alloc((size_t)NPB * EPB * 8);

  k_h<<<(NN + 63) / 64, 256, 0, stream>>>(x, W, a_src, a_dst, h16, ssrc, sdst);
  k_sort<<<NPB, 512, 0, stream>>>(ei, ssrc, cnt_cm, lpre, stage);
  k_tr<<<dim3((NPB + 31) / 32, (NBKT + 31) / 32), 256, 0, stream>>>(cnt_cm, lpre, cnt, lpreT);
  k_scanA<<<NSB, 256, 0, stream>>>(cnt, partials);
  k_scanB<<<1, 512, 0, stream>>>(partials, boff);
  k_scanC<<<NSB, 256, 0, stream>>>(cnt, partials, boff);
  k_fuse<<<NBKT, 512, 0, stream>>>(boff, cnt, lpreT, stage, sdst, h16, out);
}

// Round 14
// 86.184 us; speedup vs baseline: 1.2238x; 1.0434x over previous
//
#include <hip/hip_runtime.h>
#include <math.h>

#define NN 100000          // nodes
#define NE 1600000         // edges
#define BKB 7              // bucket bits -> 128 nodes/bucket
#define BSZ 128            // nodes per bucket
#define NBKT 782           // ceil(NN/128)
#define LPS  (NBKT + 1)    // lpre row stride (chunk-major)
#define EPB 2048           // edges per sort chunk
#define NPB ((NE + EPB - 1) / EPB)        // 782 chunks
#define TOTC (NBKT * NPB)                 // 611,524 cells (bucket-major)
#define SBLK 2048                         // scan elems per block
#define NSB ((TOTC + SBLK - 1) / SBLK)    // 299 scan blocks
#define LBUF2 2560         // per-bucket LDS entry cap (mean 2046, +11 sigma)
#define EVC 5              // LBUF2 / 512

typedef unsigned int uint;
typedef unsigned short ushort;
typedef __attribute__((ext_vector_type(8))) short bfx8;
typedef __attribute__((ext_vector_type(4))) float f32x4;

static __device__ __forceinline__ ushort f2bf(float f) {
  uint u = __float_as_uint(f);
  uint r = (u + 0x7fffu + ((u >> 16) & 1u)) >> 16;   // RNE
  return (ushort)r;
}
static __device__ __forceinline__ float bf2f(ushort v) {
  return __uint_as_float((uint)v << 16);
}
static __device__ __forceinline__ bfx8 cvt8(float4 a, float4 b) {
  bfx8 r;
  r[0] = (short)f2bf(a.x); r[1] = (short)f2bf(a.y);
  r[2] = (short)f2bf(a.z); r[3] = (short)f2bf(a.w);
  r[4] = (short)f2bf(b.x); r[5] = (short)f2bf(b.y);
  r[6] = (short)f2bf(b.z); r[7] = (short)f2bf(b.w);
  return r;
}

// ---------------- Kernel A: h = x @ W^T via bf16 MFMA, fused s_src/s_dst ----
__global__ __launch_bounds__(256) void k_h(
    const float* __restrict__ x, const float* __restrict__ W,
    const float* __restrict__ a_src, const float* __restrict__ a_dst,
    ushort* __restrict__ h16, float* __restrict__ ssrc, float* __restrict__ sdst)
{
  __shared__ __align__(16) ushort ws[64 * 128];   // 16KB
  const int t = threadIdx.x;
  const int base = blockIdx.x * 64;
  const float4* x4 = (const float4*)x;
  const float4* W4 = (const float4*)W;

#pragma unroll
  for (int q = 0; q < 8; ++q) {
    int f = q * 256 + t;
    int row = f >> 5, c4 = f & 31;
    float4 v = W4[f];
    ushort4 pk = make_ushort4(f2bf(v.x), f2bf(v.y), f2bf(v.z), f2bf(v.w));
    int byte = row * 256 + ((c4 * 8) ^ ((row & 7) << 4));
    *(ushort4*)((char*)ws + byte) = pk;
  }

  const int wid = t >> 6;
  const int lane = t & 63;
  const int lg = lane >> 4;
  const int lr = lane & 15;

  const int node = base + wid * 16 + lr;
  const bool ok = node < NN;
  const float4* xr = x4 + (size_t)node * 32;

  float4 xa[4][2];
#pragma unroll
  for (int ks = 0; ks < 4; ++ks) {
    xa[ks][0] = ok ? xr[ks * 8 + lg * 2]     : make_float4(0.f, 0.f, 0.f, 0.f);
    xa[ks][1] = ok ? xr[ks * 8 + lg * 2 + 1] : make_float4(0.f, 0.f, 0.f, 0.f);
  }
  __syncthreads();

  f32x4 acc[4];
#pragma unroll
  for (int ng = 0; ng < 4; ++ng) acc[ng] = (f32x4){0.f, 0.f, 0.f, 0.f};

#pragma unroll
  for (int ks = 0; ks < 4; ++ks) {
    int kb = ks * 64 + lg * 16;
    bfx8 af = cvt8(xa[ks][0], xa[ks][1]);
    bfx8 bfr[4];
#pragma unroll
    for (int ng = 0; ng < 4; ++ng) {
      int row = ng * 16 + lr;
      bfr[ng] = *(const bfx8*)((const char*)ws + row * 256 + (kb ^ ((row & 7) << 4)));
    }
#pragma unroll
    for (int ng = 0; ng < 4; ++ng)
      acc[ng] = __builtin_amdgcn_mfma_f32_16x16x32_bf16(af, bfr[ng], acc[ng], 0, 0, 0);
  }

  float as_[4], ad_[4];
#pragma unroll
  for (int ng = 0; ng < 4; ++ng) { as_[ng] = a_src[ng * 16 + lr]; ad_[ng] = a_dst[ng * 16 + lr]; }
#pragma unroll
  for (int r = 0; r < 4; ++r) {
    int nout = base + wid * 16 + lg * 4 + r;
    float ps = 0.f, pd = 0.f;
#pragma unroll
    for (int ng = 0; ng < 4; ++ng) { ps += acc[ng][r] * as_[ng]; pd += acc[ng][r] * ad_[ng]; }
#pragma unroll
    for (int m = 1; m < 16; m <<= 1) { ps += __shfl_xor(ps, m); pd += __shfl_xor(pd, m); }
    if (lr == 0 && nout < NN) { ssrc[nout] = ps; sdst[nout] = pd; }
    if (nout < NN) {
#pragma unroll
      for (int ng = 0; ng < 4; ++ng)
        h16[(size_t)nout * 64 + ng * 16 + lr] = f2bf(acc[ng][r]);
    }
  }
}

// ---------------- k_sort: per-chunk bucket sort in LDS, 4B entries --------------
// stage[c*EPB+i] = src | dl<<24 (dl = dst&127). No ssrc gather here (k_fuse does it).
__global__ __launch_bounds__(512) void k_sort(const int* __restrict__ ei,
                                              int* __restrict__ cnt_cm,
                                              int* __restrict__ lpre,
                                              int* __restrict__ stage)
{
  __shared__ int hh[NBKT];
  __shared__ int sums[512];
  __shared__ int sbuf[EPB];    // 8KB
  const int t = threadIdx.x, c = blockIdx.x;
  for (int i = t; i < NBKT; i += 512) hh[i] = 0;
  __syncthreads();

  const int base = c * EPB;
  const int nloc = min(EPB, NE - base);
  int my_src[EPB / 512], my_dst[EPB / 512];
#pragma unroll
  for (int q = 0; q < EPB / 512; ++q) {
    int e = base + q * 512 + t;
    if (e < NE) {
      my_src[q] = ei[e];
      my_dst[q] = ei[NE + e];
      atomicAdd(&hh[my_dst[q] >> BKB], 1);
    } else my_dst[q] = -1;
  }
  __syncthreads();

  // exclusive scan of hh[NBKT], 2 elems/thread
  int i0 = 2 * t, i1 = 2 * t + 1;
  int v0 = (i0 < NBKT) ? hh[i0] : 0;
  int v1 = (i1 < NBKT) ? hh[i1] : 0;
  sums[t] = v0 + v1;
  __syncthreads();
  for (int off = 1; off < 512; off <<= 1) {
    int u = (t >= off) ? sums[t - off] : 0;
    __syncthreads();
    sums[t] += u;
    __syncthreads();
  }
  int ex0 = sums[t] - (v0 + v1);
  if (i0 < NBKT) {
    hh[i0] = ex0;
    lpre[c * LPS + i0] = ex0;
    cnt_cm[(size_t)c * NBKT + i0] = v0;
  }
  if (i1 < NBKT) {
    hh[i1] = ex0 + v0;
    lpre[c * LPS + i1] = ex0 + v0;
    cnt_cm[(size_t)c * NBKT + i1] = v1;
  }
  if (t == 0) lpre[c * LPS + NBKT] = nloc;
  __syncthreads();

#pragma unroll
  for (int q = 0; q < EPB / 512; ++q) {
    if (my_dst[q] >= 0) {
      int dst = my_dst[q], src = my_src[q];
      int pos = atomicAdd(&hh[dst >> BKB], 1);
      sbuf[pos] = src | ((dst & (BSZ - 1)) << 24);
    }
  }
  __syncthreads();
#pragma unroll
  for (int q = 0; q < EPB / 512; ++q) {
    int i = q * 512 + t;
    if (i < nloc) stage[base + i] = sbuf[i];
  }
}

// ---------------- k_tr: transpose cnt_cm and lpre to bucket-major ---------------
__global__ __launch_bounds__(256) void k_tr(const int* __restrict__ cnt_cm,
                                            const int* __restrict__ lpre,
                                            int* __restrict__ cnt,
                                            int* __restrict__ lpreT)
{
  __shared__ int tileA[32][33];
  __shared__ int tileB[32][33];
  int cb = blockIdx.x * 32, bb = blockIdx.y * 32;
  int tx = threadIdx.x & 31, ty = threadIdx.x >> 5;   // 32x8
  for (int r = ty; r < 32; r += 8) {
    int c = cb + r, b = bb + tx;
    bool in = (c < NPB && b < NBKT);
    tileA[r][tx] = in ? cnt_cm[(size_t)c * NBKT + b] : 0;
    tileB[r][tx] = in ? lpre[(size_t)c * LPS + b] : 0;
  }
  __syncthreads();
  for (int r = ty; r < 32; r += 8) {
    int b = bb + r, c = cb + tx;
    if (b < NBKT && c < NPB) {
      cnt[(size_t)b * NPB + c] = tileA[tx][r];
      lpreT[(size_t)b * NPB + c] = tileB[tx][r];
    }
  }
}

// ---------------- 3-pass grid-parallel exclusive scan of cnt[TOTC] --------------
__global__ __launch_bounds__(256) void k_scanA(const int* __restrict__ cnt,
                                               int* __restrict__ partials)
{
  __shared__ int sm[256];
  int t = threadIdx.x, b = blockIdx.x;
  const int4* c4 = (const int4*)(cnt + b * SBLK + t * 8);
  int4 u = c4[0], v = c4[1];
  sm[t] = u.x + u.y + u.z + u.w + v.x + v.y + v.z + v.w;
  __syncthreads();
  for (int s = 128; s > 0; s >>= 1) { if (t < s) sm[t] += sm[t + s]; __syncthreads(); }
  if (t == 0) partials[b] = sm[0];
}

__global__ __launch_bounds__(512) void k_scanB(int* __restrict__ partials,
                                               int* __restrict__ boff)
{
  __shared__ int sm[512];
  int t = threadIdx.x;
  int v = (t < NSB) ? partials[t] : 0;
  sm[t] = v;
  __syncthreads();
  for (int off = 1; off < 512; off <<= 1) {
    int u = (t >= off) ? sm[t - off] : 0;
    __syncthreads();
    sm[t] += u;
    __syncthreads();
  }
  if (t < NSB) partials[t] = sm[t] - v;   // exclusive
  if (t == 0) boff[NBKT] = NE;
}

__global__ __launch_bounds__(256) void k_scanC(int* __restrict__ cnt,
                                               const int* __restrict__ partials,
                                               int* __restrict__ boff)
{
  __shared__ int sm[256];
  int t = threadIdx.x, b = blockIdx.x;
  int base = b * SBLK + t * 8;
  int4* c4 = (int4*)(cnt + base);
  int4 u = c4[0], v = c4[1];
  int tot = u.x + u.y + u.z + u.w + v.x + v.y + v.z + v.w;
  sm[t] = tot;
  __syncthreads();
  for (int off = 1; off < 256; off <<= 1) {
    int w = (t >= off) ? sm[t - off] : 0;
    __syncthreads();
    sm[t] += w;
    __syncthreads();
  }
  int run = partials[b] + sm[t] - tot;
  int e[8] = {u.x, u.y, u.z, u.w, v.x, v.y, v.z, v.w};
  int ex[8];
#pragma unroll
  for (int k = 0; k < 8; ++k) { ex[k] = run; run += e[k]; }
#pragma unroll
  for (int k = 0; k < 8; ++k) {
    int idx = base + k;
    if (idx < TOTC && idx % NPB == 0) boff[idx / NPB] = ex[k];
  }
  c4[0] = make_int4(ex[0], ex[1], ex[2], ex[3]);
  c4[1] = make_int4(ex[4], ex[5], ex[6], ex[7]);
}

// ---------------- k_fuse: binary-search gather (+ssrc) -> node-sort -> aggregate -
__global__ __launch_bounds__(512) void k_fuse(const int* __restrict__ boff,
                                              const int* __restrict__ pcnt,  // scanned cnt
                                              const int* __restrict__ lpreT,
                                              const int* __restrict__ stage,
                                              const float* __restrict__ ssrc,
                                              const float* __restrict__ sdst,
                                              const ushort* __restrict__ h16,
                                              float* __restrict__ out)
{
  __shared__ int2 lbuf[LBUF2];    // 20KB (node-sorted entries)
  __shared__ int pcl[NPB + 1];    // run starts (rel), ascending
  __shared__ int lpb[NPB];        // within-chunk run starts
  __shared__ int nh[BSZ];         // hist -> pristine node starts
  __shared__ int nst[BSZ];        // inclusive scan (node ends)
  __shared__ int cur[BSZ];        // mutable cursors
  __shared__ float sdl[BSZ];
  const int b = blockIdx.x, t = threadIdx.x;
  const int e_beg = boff[b], e_end = boff[b + 1];
  const int m = e_end - e_beg;

  // phase 0: stage tables (coalesced rows), init hist
  for (int j = t; j < NPB; j += 512) {
    pcl[j] = pcnt[(size_t)b * NPB + j] - e_beg;
    lpb[j] = lpreT[(size_t)b * NPB + j];
  }
  if (t == 0) pcl[NPB] = m;
  if (t < BSZ) {
    nh[t] = 0;
    int node = (b << BKB) + t;
    sdl[t] = (node < NN) ? sdst[node] : 0.f;
  }
  __syncthreads();

  // phase 1: binary search -> stage load -> issue ssrc gather (hidden by phase 2)
  int ev[EVC];
  float ssv[EVC];
  int ne = 0;
#pragma unroll
  for (int q = 0; q < EVC; ++q) {
    int i = q * 512 + t;
    if (i < m) {
      int lo = 0, hi = NPB;
      while (hi - lo > 1) { int mid = (lo + hi) >> 1; if (pcl[mid] <= i) lo = mid; else hi = mid; }
      ev[q] = stage[(size_t)lo * EPB + lpb[lo] + (i - pcl[lo])];
      ssv[q] = ssrc[ev[q] & 0xFFFFFF];     // L2/L3-resident 400KB, consumed in phase 3
      atomicAdd(&nh[((uint)ev[q]) >> 24], 1);
      ne = q + 1;
    }
  }
  __syncthreads();

  // phase 2: node-start scan
  int v0 = (t < BSZ) ? nh[t] : 0;
  if (t < BSZ) nst[t] = v0;
  __syncthreads();
  for (int off = 1; off < BSZ; off <<= 1) {
    int u = (t >= off && t < BSZ) ? nst[t - off] : 0;
    __syncthreads();
    if (t < BSZ) nst[t] += u;
    __syncthreads();
  }
  if (t < BSZ) { int ex = nst[t] - v0; cur[t] = ex; nh[t] = ex; }  // nh = pristine starts
  __syncthreads();

  // phase 3: permute into node-sorted lbuf, alpha computed here
  int slots[EVC];
  float alph[EVC];
#pragma unroll
  for (int q = 0; q < EVC; ++q) {
    if (q < ne) {
      int dl = ((uint)ev[q]) >> 24;
      slots[q] = atomicAdd(&cur[dl], 1);
      float e = ssv[q] + sdl[dl];
      e = (e >= 0.f) ? e : 0.2f * e;           // LeakyReLU(0.2)
      e = fminf(fmaxf(e, -10.f), 10.f);        // clip
      alph[q] = __expf(e);
    }
  }
#pragma unroll
  for (int q = 0; q < EVC; ++q)
    if (q < ne) lbuf[slots[q]] = make_int2(ev[q] & 0xFFFFFF, __float_as_int(alph[q]));
  __syncthreads();

  // phase 4: aggregation — 32 streams x 16 lanes, 4 nodes/stream, uint4 gathers
  const int sid = t >> 4;
  const int l16 = t & 15;
  const int half = l16 >> 3, l8 = l16 & 7;
  const uint4* h4 = (const uint4*)h16;
#pragma unroll
  for (int r = 0; r < 4; ++r) {
    int nl = sid + 32 * r;
    int beg = nh[nl];
    int end = nst[nl];
    float a0 = 0.f, a1 = 0.f, a2 = 0.f, a3 = 0.f;
    float a4 = 0.f, a5 = 0.f, a6 = 0.f, a7 = 0.f;
    float den = 0.f;
    int last = end - 1;
    for (int j = beg; j < end; j += 8) {
#pragma unroll
      for (int p = 0; p < 4; ++p) {
        int idx = j + p * 2 + half;
        int2 e = lbuf[min(idx, last)];
        float a = (idx < end) ? __int_as_float(e.y) : 0.f;
        uint4 hq = h4[(size_t)e.x * 8 + l8];
        den += a;
        a0 += a * bf2f((ushort)(hq.x & 0xffff));
        a1 += a * bf2f((ushort)(hq.x >> 16));
        a2 += a * bf2f((ushort)(hq.y & 0xffff));
        a3 += a * bf2f((ushort)(hq.y >> 16));
        a4 += a * bf2f((ushort)(hq.z & 0xffff));
        a5 += a * bf2f((ushort)(hq.z >> 16));
        a6 += a * bf2f((ushort)(hq.w & 0xffff));
        a7 += a * bf2f((ushort)(hq.w >> 16));
      }
    }
    a0 += __shfl_xor(a0, 8);
    a1 += __shfl_xor(a1, 8);
    a2 += __shfl_xor(a2, 8);
    a3 += __shfl_xor(a3, 8);
    a4 += __shfl_xor(a4, 8);
    a5 += __shfl_xor(a5, 8);
    a6 += __shfl_xor(a6, 8);
    a7 += __shfl_xor(a7, 8);
    den += __shfl_xor(den, 8);
    int node = (b << BKB) + nl;
    if (node < NN) {
      float inv = 1.f / (den + 1e-9f);
      float4 o = half ? make_float4(a4 * inv, a5 * inv, a6 * inv, a7 * inv)
                      : make_float4(a0 * inv, a1 * inv, a2 * inv, a3 * inv);
      ((float4*)out)[(size_t)node * 16 + l8 * 2 + half] = o;
    }
  }
}

extern "C" void kernel_launch(void* const* d_in, const int* in_sizes, int n_in,
                              void* d_out, int out_size, void* d_ws, size_t ws_size,
                              hipStream_t stream)
{
  const float* x     = (const float*)d_in[0];
  const int*   ei    = (const int*)d_in[1];
  const float* W     = (const float*)d_in[2];
  const float* a_src = (const float*)d_in[3];
  const float* a_dst = (const float*)d_in[4];
  float* out = (float*)d_out;

  char* p = (char*)d_ws;
  auto alloc = [&](size_t bytes) -> char* {
    char* r = p;
    p += (bytes + 255) & ~(size_t)255;
    return r;
  };
  ushort* h16    = (ushort*)alloc((size_t)NN * 64 * 2);
  float* ssrc    = (float*)alloc((size_t)NN * 4);
  float* sdst    = (float*)alloc((size_t)NN * 4);
  int*   cnt     = (int*)alloc((size_t)NSB * SBLK * 4);   // padded past TOTC
  int*   cnt_cm  = (int*)alloc((size_t)NPB * NBKT * 4);
  int*   lpre    = (int*)alloc((size_t)NPB * LPS * 4);
  int*   lpreT   = (int*)alloc((size_t)NBKT * NPB * 4);
  int*   boff    = (int*)alloc((size_t)(NBKT + 1) * 4);
  int*   partials= (int*)alloc((size_t)NSB * 4);
  int*   stage   = (int*)alloc((size_t)NPB * EPB * 4);

  k_h<<<(NN + 63) / 64, 256, 0, stream>>>(x, W, a_src, a_dst, h16, ssrc, sdst);
  k_sort<<<NPB, 512, 0, stream>>>(ei, cnt_cm, lpre, stage);
  k_tr<<<dim3((NPB + 31) / 32, (NBKT + 31) / 32), 256, 0, stream>>>(cnt_cm, lpre, cnt, lpreT);
  k_scanA<<<NSB, 256, 0, stream>>>(cnt, partials);
  k_scanB<<<1, 512, 0, stream>>>(partials, boff);
  k_scanC<<<NSB, 256, 0, stream>>>(cnt, partials, boff);
  k_fuse<<<NBKT, 512, 0, stream>>>(boff, cnt, lpreT, stage, ssrc, sdst, h16, out);
}